// Round 28
// baseline (850.666 us; speedup 1.0000x reference)
//
#include <hip/hip_runtime.h>
#include <hip/hip_bf16.h>

#define LNUM 4
#define ENUM 12
#define CH 256
#define MLP 128
#define HW 196
#define BNUM 128
#define ROWLEN 14
#define MTOT (BNUM * HW)   // 25088 rows
#define MAXT128 208        // TM=128 tiles: 196 full + <=12 partial
#define MAXT64 416         // TM=64 tiles: 392 full + <=12 partial
#define RSLICE 7           // router mean-pool slices per batch (28 rows each)

// packed per-layer weight plane offsets (ushort elements)
#define PK_WQ 0
#define PK_WK 786432
#define PK_WV 1572864
#define PK_WO 2359296
#define PK_W1 3145728
#define PK_W2 3538944
#define PK_TOTAL 3932160

using bf16x8 = __attribute__((ext_vector_type(8))) short;
using f32x4 = __attribute__((ext_vector_type(4))) float;

__device__ inline unsigned short f2bf(float v) {
  __hip_bfloat16 b = __float2bfloat16(v);   // RNE
  return *reinterpret_cast<unsigned short*>(&b);
}
__device__ inline float bf2f(unsigned short u) {
  union { unsigned int i; float f; } cv;
  cv.i = ((unsigned int)u) << 16;
  return cv.f;
}
__device__ inline void split_bf(float v, unsigned short& hi, unsigned short& lo) {
  hi = f2bf(v);
  lo = f2bf(v - bf2f(hi));
}
// async global->LDS 16B per lane; dest = uniform base + lane*16; src per-lane
__device__ inline void gload16(const void* g, void* l) {
  __builtin_amdgcn_global_load_lds(
      (const __attribute__((address_space(1))) unsigned int*)g,
      (__attribute__((address_space(3))) unsigned int*)l, 16, 0, 0);
}

// ---------------------------------------------------------------------------
__global__ __launch_bounds__(256) void transpose_stem(const float* __restrict__ stem,
                                                      float* __restrict__ x,
                                                      int* __restrict__ rcnt) {
  if (blockIdx.x == 0 && blockIdx.y == 0 && blockIdx.z == 0 &&
      threadIdx.x == 0 && threadIdx.y == 0)
    rcnt[0] = 0;
  __shared__ float tile[32][33];
  int b = blockIdx.z;
  int c0 = blockIdx.x * 32;
  int p0 = blockIdx.y * 32;
  int tx = threadIdx.x;
  int ty = threadIdx.y;
  for (int i = ty; i < 32; i += 8) {
    int c = c0 + i, p = p0 + tx;
    if (p < HW) tile[i][tx] = stem[(size_t)b * CH * HW + (size_t)c * HW + p];
  }
  __syncthreads();
  for (int i = ty; i < 32; i += 8) {
    int p = p0 + i, c = c0 + tx;
    if (p < HW) x[(size_t)b * HW * CH + (size_t)p * CH + c] = tile[tx][i];
  }
}

// ---------------------------------------------------------------------------
// Router stage A: grid-parallel mean-pool partials. 896 blocks = 128 batches
// x 7 slices (28 rows each; 4 waves x 7 rows, 7-deep float4 batch). No sync.
__global__ __launch_bounds__(256) void router_mean(
    const float* __restrict__ x, float* __restrict__ psum) {
  int bid = blockIdx.x;            // 0..BNUM*RSLICE-1
  int b = bid / RSLICE, s = bid - b * RSLICE;
  int tid = threadIdx.x;
  int w = tid >> 6, lane = tid & 63;
  const float* xb = x + (size_t)b * HW * CH;
  float a0 = 0.f, a1 = 0.f, a2 = 0.f, a3 = 0.f;
  int p0 = s * 28 + w * 7;
  {
    float4 t[7];
#pragma unroll
    for (int i = 0; i < 7; ++i)
      t[i] = *reinterpret_cast<const float4*>(
          &xb[(size_t)(p0 + i) * CH + lane * 4]);
#pragma unroll
    for (int i = 0; i < 7; ++i) {
      a0 += t[i].x; a1 += t[i].y; a2 += t[i].z; a3 += t[i].w;
    }
  }
  __shared__ float rsum[4][CH];
  rsum[w][lane * 4 + 0] = a0;
  rsum[w][lane * 4 + 1] = a1;
  rsum[w][lane * 4 + 2] = a2;
  rsum[w][lane * 4 + 3] = a3;
  __syncthreads();
  if (tid < CH)
    psum[(size_t)bid * CH + tid] =
        rsum[0][tid] + rsum[1][tid] + rsum[2][tid] + rsum[3][tid];
}

// ---------------------------------------------------------------------------
// Router stage B: combine partials (fixed slice order), logits/softmax/argmax;
// last block (device-scope atomic, round-19-proven) builds tile tables.
__global__ __launch_bounds__(256) void router_finish(
    const float* __restrict__ psum, const float* __restrict__ gate_w,
    const float* __restrict__ gate_b, float* __restrict__ probs_out,
    float* __restrict__ idx_out, float* __restrict__ weight,
    int* __restrict__ eidx, int* __restrict__ rcnt, int* __restrict__ perm,
    int* __restrict__ te128, int* __restrict__ tr0128, int* __restrict__ trw128,
    int* __restrict__ te64, int* __restrict__ tr064, int* __restrict__ trw64,
    int li) {
  int b = blockIdx.x;
  int tid = threadIdx.x;
  __shared__ float r[CH];
  {
    float acc = 0.f;
#pragma unroll
    for (int ss = 0; ss < RSLICE; ++ss)
      acc += psum[((size_t)b * RSLICE + ss) * CH + tid];
    r[tid] = acc * (1.0f / (float)HW);
  }
  __syncthreads();
  __shared__ float part[ENUM][16];
  if (tid < 192) {
    int e = tid >> 4, seg = tid & 15;
    const float* gw = gate_w + (size_t)li * CH * ENUM;
    float acc = 0.f;
#pragma unroll
    for (int kk = 0; kk < 16; ++kk) {
      int k = seg * 16 + kk;
      acc += r[k] * gw[(size_t)k * ENUM + e];
    }
    part[e][seg] = acc;
  }
  __syncthreads();
  __shared__ float logits[ENUM];
  if (tid < ENUM) {
    float acc = gate_b[li * ENUM + tid];
#pragma unroll
    for (int seg = 0; seg < 16; ++seg) acc += part[tid][seg];
    logits[tid] = acc;
  }
  __syncthreads();
  __shared__ int last;
  if (tid == 0) {
    float mx = logits[0]; int am = 0;
    for (int e = 1; e < ENUM; ++e) if (logits[e] > mx) { mx = logits[e]; am = e; }
    float pr[ENUM]; float den = 0.f;
    for (int e = 0; e < ENUM; ++e) { pr[e] = expf(logits[e] - mx); den += pr[e]; }
    float inv = 1.0f / den;
    for (int e = 0; e < ENUM; ++e) pr[e] *= inv;
    for (int e = 0; e < ENUM; ++e)
      probs_out[(size_t)(li * BNUM + b) * ENUM + e] = pr[e];
    idx_out[li * BNUM + b] = (float)am;
    float pmax = pr[am];
    weight[b] = pmax / (pmax + 1e-8f);
    eidx[b] = am;
    __threadfence();                       // release eidx before counting in
    int old = atomicAdd(rcnt, 1);
    last = (old == BNUM - 1) ? 1 : 0;
  }
  __syncthreads();
  if (!last) return;
  __threadfence();                         // acquire: see all blocks' eidx
  __shared__ int cnt[ENUM], start[ENUM];
  int t = tid;
  if (t < ENUM) {
    int cc = 0;
    for (int bb = 0; bb < BNUM; ++bb) if (eidx[bb] == t) ++cc;
    cnt[t] = cc;
  }
  __syncthreads();
  if (t == 0) {
    int ss = 0;
    for (int e = 0; e < ENUM; ++e) { start[e] = ss; ss += cnt[e]; }
  }
  __syncthreads();
  if (t < ENUM) {
    int pos = start[t];
    for (int bb = 0; bb < BNUM; ++bb) if (eidx[bb] == t) perm[pos++] = bb;
  }
  if (t == 0) {
    int tile = 0;
    for (int e = 0; e < ENUM; ++e) {
      int rows = cnt[e] * HW;
      int row0 = start[e] * HW;
      int off = 0;
      while (off < rows) {
        te128[tile] = e;
        tr0128[tile] = row0 + off;
        int rem = rows - off;
        trw128[tile] = rem < 128 ? rem : 128;
        ++tile; off += 128;
      }
    }
    for (; tile < MAXT128; ++tile) { trw128[tile] = 0; te128[tile] = 0; tr0128[tile] = 0; }
    rcnt[0] = 0;                           // reset for next layer
  } else if (t == 1) {
    int tile = 0;
    for (int e = 0; e < ENUM; ++e) {
      int rows = cnt[e] * HW;
      int row0 = start[e] * HW;
      int off = 0;
      while (off < rows) {
        te64[tile] = e;
        tr064[tile] = row0 + off;
        int rem = rows - off;
        trw64[tile] = rem < 64 ? rem : 64;
        ++tile; off += 64;
      }
    }
    for (; tile < MAXT64; ++tile) { trw64[tile] = 0; te64[tile] = 0; tr064[tile] = 0; }
  }
}

// ---------------------------------------------------------------------------
// Pre-split + pre-pack weights: [K/8][N][8] bf16 hi/lo per (layer, expert).
__global__ __launch_bounds__(256) void prepack(
    const float* __restrict__ wq, const float* __restrict__ wk,
    const float* __restrict__ wv, const float* __restrict__ wo,
    const float* __restrict__ w1, const float* __restrict__ w2,
    unsigned short* __restrict__ Phi, unsigned short* __restrict__ Plo,
    int li0, int plane_mult) {
  int lz = blockIdx.z / ENUM;
  int e = blockIdx.z % ENUM;
  int li = li0 + lz;
  size_t plane = (size_t)lz * plane_mult;
  int ts = blockIdx.y;    // 6
  int K = (ts == 5) ? 128 : 256;
  int N = (ts == 4) ? 128 : 256;
  int total = (K / 8) * N;
  int id = blockIdx.x * 256 + threadIdx.x;
  if (id >= total) return;
  const float* src;
  size_t dst0;
  switch (ts) {
    case 0: src = wq; dst0 = PK_WQ; break;
    case 1: src = wk; dst0 = PK_WK; break;
    case 2: src = wv; dst0 = PK_WV; break;
    case 3: src = wo; dst0 = PK_WO; break;
    case 4: src = w1; dst0 = PK_W1; break;
    default: src = w2; dst0 = PK_W2; break;
  }
  src += ((size_t)li * ENUM + e) * K * N;
  size_t dst = plane + dst0 + (size_t)e * K * N;
  int n = id % N;
  int kg = id / N;
  const float* sp = src + (size_t)kg * 8 * N + n;
  unsigned short hs[8], ls[8];
#pragma unroll
  for (int j = 0; j < 8; ++j) split_bf(sp[(size_t)j * N], hs[j], ls[j]);
  uint4 ph, pl;
  ph.x = hs[0] | ((unsigned)hs[1] << 16); ph.y = hs[2] | ((unsigned)hs[3] << 16);
  ph.z = hs[4] | ((unsigned)hs[5] << 16); ph.w = hs[6] | ((unsigned)hs[7] << 16);
  pl.x = ls[0] | ((unsigned)ls[1] << 16); pl.y = ls[2] | ((unsigned)ls[3] << 16);
  pl.z = ls[4] | ((unsigned)ls[5] << 16); pl.w = ls[6] | ((unsigned)ls[7] << 16);
  size_t o = dst + (size_t)(kg * N + n) * 8;
  *reinterpret_cast<uint4*>(Phi + o) = ph;
  *reinterpret_cast<uint4*>(Plo + o) = pl;
}

// ---------------------------------------------------------------------------
// LayerNorm: one WAVE per token (4 tokens/block), no barriers, vectorized.
__global__ __launch_bounds__(256) void ln_kernel(
    const float* __restrict__ xin, unsigned short* __restrict__ hhi,
    unsigned short* __restrict__ hlo,
    const float* __restrict__ g, const float* __restrict__ bta,
    const int* __restrict__ eidx, const int* __restrict__ perm, int li) {
  int tok = blockIdx.x * 4 + (threadIdx.x >> 6);   // sorted token id
  int lane = threadIdx.x & 63;
  int s = tok / HW, p = tok - s * HW;
  int b = perm[s];
  int e = eidx[b];
  float4 vx = *reinterpret_cast<const float4*>(
      &xin[((size_t)b * HW + p) * CH + lane * 4]);
  float sm = vx.x + vx.y + vx.z + vx.w;
#pragma unroll
  for (int off = 1; off < 64; off <<= 1) sm += __shfl_xor(sm, off, 64);
  float mu = sm * (1.0f / (float)CH);
  float d0 = vx.x - mu, d1 = vx.y - mu, d2 = vx.z - mu, d3 = vx.w - mu;
  float s2 = d0 * d0 + d1 * d1 + d2 * d2 + d3 * d3;
#pragma unroll
  for (int off = 1; off < 64; off <<= 1) s2 += __shfl_xor(s2, off, 64);
  float rs = rsqrtf(s2 * (1.0f / (float)CH) + 1e-5f);
  size_t gb = ((size_t)li * ENUM + e) * CH + lane * 4;
  float4 gg = *reinterpret_cast<const float4*>(&g[gb]);
  float4 bb = *reinterpret_cast<const float4*>(&bta[gb]);
  float h0 = d0 * rs * gg.x + bb.x;
  float h1 = d1 * rs * gg.y + bb.y;
  float h2 = d2 * rs * gg.z + bb.z;
  float h3 = d3 * rs * gg.w + bb.w;
  ushort4 vh, vl;
  split_bf(h0, vh.x, vl.x);
  split_bf(h1, vh.y, vl.y);
  split_bf(h2, vh.z, vl.z);
  split_bf(h3, vh.w, vl.w);
  size_t ob = (size_t)tok * CH + lane * 4;
  *reinterpret_cast<ushort4*>(&hhi[ob]) = vh;
  *reinterpret_cast<ushort4*>(&hlo[ob]) = vl;
}

// ---------------------------------------------------------------------------
// Split-bf16 MFMA grouped GEMM, TM_ x 128 tile, async LDS stage, single buf,
// 2 barriers / K-step, XCD-chunked bijective block swizzle. (round-13 proven)
// EPI: 0 QKV fp32 store | 2 +X via perm
template <int EPI, int NT, int KDIM, int NXTOT, int TM_, int NTILE>
__global__ __launch_bounds__(256) void gemm_mfma(
    const unsigned short* __restrict__ Ahi, const unsigned short* __restrict__ Alo,
    const unsigned short* __restrict__ Whi, const unsigned short* __restrict__ Wlo,
    size_t wbase, size_t wstride,
    const float* __restrict__ B0, const float* __restrict__ B1p, const float* __restrict__ B2p,
    float* __restrict__ O0, float* __restrict__ O1p, float* __restrict__ O2p,
    float* __restrict__ X,
    const int* __restrict__ tile_e, const int* __restrict__ tile_row0,
    const int* __restrict__ tile_rows, const int* __restrict__ perm, int li) {
  constexpr int NX = NT / 128;
  constexpr int NSTEP = KDIM / 32;
  constexpr int FM = TM_ / 32;
  constexpr int NSEG = TM_ / 64;
  int nwg = NXTOT * NTILE;
  int orig = blockIdx.x;
  int q = nwg >> 3, r = nwg & 7;
  int xcd = orig & 7, idx = orig >> 3;
  int wg = (xcd < r ? xcd * (q + 1) : r * (q + 1) + (xcd - r) * q) + idx;
  int tileid = wg / NXTOT;
  int cbx = wg % NXTOT;

  int rows = tile_rows[tileid];
  if (rows <= 0) return;
  int row0 = tile_row0[tileid];
  int e = tile_e[tileid];
  int cb = cbx / NX;
  int ncol0 = (cbx % NX) * 128;

  const float* Bt = (EPI == 0) ? (cb == 0 ? B0 : (cb == 1 ? B1p : B2p)) : B0;
  float* Oo = (EPI == 0) ? (cb == 0 ? O0 : (cb == 1 ? O1p : O2p)) : O0;
  size_t woff = wbase + (size_t)cb * wstride + (size_t)e * (KDIM * NT);
  const unsigned short* Wh = Whi + woff;
  const unsigned short* Wl = Wlo + woff;
  const float* bias = Bt + ((size_t)li * ENUM + e) * NT + ncol0;

  __shared__ unsigned short Ash[4][TM_][8], Asl[4][TM_][8];
  __shared__ unsigned short Bsh[4][128][8], Bsl[4][128][8];

  int tid = threadIdx.x;
  int lane = tid & 63, w = tid >> 6;
  int wr = w >> 1, wc = w & 1;
  int r0w = wr * (TM_ / 2), c0w = wc * 64;
  int lrow = lane & 15, lk = lane >> 4;

  const unsigned short* gAh[NSEG];
  const unsigned short* gAl[NSEG];
#pragma unroll
  for (int s = 0; s < NSEG; ++s) {
    int rl = (s * 64 + lane < rows) ? s * 64 + lane : 0;
    gAh[s] = Ahi + (size_t)(row0 + rl) * KDIM + w * 8;
    gAl[s] = Alo + (size_t)(row0 + rl) * KDIM + w * 8;
  }

  f32x4 acc[FM][4];
#pragma unroll
  for (int i = 0; i < FM; ++i)
#pragma unroll
    for (int j = 0; j < 4; ++j) acc[i][j] = (f32x4){0.f, 0.f, 0.f, 0.f};

#pragma unroll
  for (int t = 0; t < NSTEP; ++t) {
    int k0 = t * 32;
#pragma unroll
    for (int s = 0; s < NSEG; ++s) {
      gload16(gAh[s] + k0, &Ash[w][s * 64][0]);
      gload16(gAl[s] + k0, &Asl[w][s * 64][0]);
    }
    const unsigned short* gBh = Wh + ((size_t)(t * 4 + w) * NT + ncol0 + lane) * 8;
    const unsigned short* gBl = Wl + ((size_t)(t * 4 + w) * NT + ncol0 + lane) * 8;
    gload16(gBh, &Bsh[w][0][0]);
    gload16(gBh + 64 * 8, &Bsh[w][64][0]);
    gload16(gBl, &Bsl[w][0][0]);
    gload16(gBl + 64 * 8, &Bsl[w][64][0]);
    __syncthreads();
    bf16x8 bh[4], bl[4];
#pragma unroll
    for (int fj = 0; fj < 4; ++fj) {
      bh[fj] = *reinterpret_cast<const bf16x8*>(&Bsh[lk][c0w + fj * 16 + lrow][0]);
      bl[fj] = *reinterpret_cast<const bf16x8*>(&Bsl[lk][c0w + fj * 16 + lrow][0]);
    }
#pragma unroll
    for (int fi = 0; fi < FM; ++fi) {
      bf16x8 ah = *reinterpret_cast<const bf16x8*>(&Ash[lk][r0w + fi * 16 + lrow][0]);
      bf16x8 al = *reinterpret_cast<const bf16x8*>(&Asl[lk][r0w + fi * 16 + lrow][0]);
#pragma unroll
      for (int fj = 0; fj < 4; ++fj) {
        acc[fi][fj] = __builtin_amdgcn_mfma_f32_16x16x32_bf16(ah, bh[fj], acc[fi][fj], 0, 0, 0);
        acc[fi][fj] = __builtin_amdgcn_mfma_f32_16x16x32_bf16(ah, bl[fj], acc[fi][fj], 0, 0, 0);
        acc[fi][fj] = __builtin_amdgcn_mfma_f32_16x16x32_bf16(al, bh[fj], acc[fi][fj], 0, 0, 0);
      }
    }
    __syncthreads();
  }

#pragma unroll
  for (int fi = 0; fi < FM; ++fi) {
#pragma unroll
    for (int r2 = 0; r2 < 4; ++r2) {
      int row_l = r0w + fi * 16 + lk * 4 + r2;
      if (row_l >= rows) continue;
      int rg = row0 + row_l;
      size_t gxb = 0;
      if (EPI == 2) {
        int s = rg / HW, p = rg - s * HW;
        gxb = ((size_t)perm[s] * HW + p) * CH;
      }
#pragma unroll
      for (int fj = 0; fj < 4; ++fj) {
        int col = c0w + fj * 16 + lrow;
        int ocol = ncol0 + col;
        float v = acc[fi][fj][r2] + bias[col];
        if (EPI == 0) {
          Oo[(size_t)rg * NT + ocol] = v;
        } else {
          X[gxb + ocol] += v;
        }
      }
    }
  }
}

// ---------------------------------------------------------------------------
// Fused MLP: W1 GEMM (64x128, K=256) -> bias+GELU+split -> m-tile in LDS
// (W2 A-fragment layout) -> W2 GEMM (64x256, K=128) -> residual+scale+dual.
__global__ __launch_bounds__(256) void fused_mlp(
    const unsigned short* __restrict__ Ahi, const unsigned short* __restrict__ Alo,
    const unsigned short* __restrict__ Whi, const unsigned short* __restrict__ Wlo,
    size_t plane, const float* __restrict__ b1, const float* __restrict__ b2,
    float* __restrict__ Oout, float* __restrict__ X, const float* __restrict__ wgt,
    const int* __restrict__ tile_e, const int* __restrict__ tile_row0,
    const int* __restrict__ tile_rows, const int* __restrict__ perm, int li) {
  int nwg = MAXT64;
  int orig = blockIdx.x;
  int q = nwg >> 3, r = nwg & 7;
  int xcd = orig & 7, idx = orig >> 3;
  int tileid = (xcd < r ? xcd * (q + 1) : r * (q + 1) + (xcd - r) * q) + idx;

  int rows = tile_rows[tileid];
  if (rows <= 0) return;
  int row0 = tile_row0[tileid];
  int e = tile_e[tileid];

  const unsigned short* W1h = Whi + plane + PK_W1 + (size_t)e * (CH * MLP);
  const unsigned short* W1l = Wlo + plane + PK_W1 + (size_t)e * (CH * MLP);
  const unsigned short* W2h = Whi + plane + PK_W2 + (size_t)e * (MLP * CH);
  const unsigned short* W2l = Wlo + plane + PK_W2 + (size_t)e * (MLP * CH);
  const float* bias1 = b1 + ((size_t)li * ENUM + e) * MLP;
  const float* bias2 = b2 + ((size_t)li * ENUM + e) * CH;

  __shared__ __align__(16) unsigned short smem[32768];
  unsigned short* Am_h = smem;                 // [16][64][8]
  unsigned short* Am_l = smem + 8192;
  unsigned short* S = smem + 16384;
  unsigned short* Ash = S;
  unsigned short* Asl = S + 2048;
  unsigned short* Bsh = S + 4096;
  unsigned short* Bsl = S + 8192;
  unsigned short* B2h = S;
  unsigned short* B2l = S + 8192;

  int tid = threadIdx.x;
  int lane = tid & 63, w = tid >> 6;
  int wr = w >> 1, wc = w & 1;
  int r0w = wr * 32, c0w = wc * 64;
  int lrow = lane & 15, lk = lane >> 4;

  int rl = (lane < rows) ? lane : 0;
  const unsigned short* gAh = Ahi + (size_t)(row0 + rl) * CH + w * 8;
  const unsigned short* gAl = Alo + (size_t)(row0 + rl) * CH + w * 8;

  f32x4 acc1[2][4];
#pragma unroll
  for (int i = 0; i < 2; ++i)
#pragma unroll
    for (int j = 0; j < 4; ++j) acc1[i][j] = (f32x4){0.f, 0.f, 0.f, 0.f};

#pragma unroll
  for (int t = 0; t < 8; ++t) {
    int k0 = t * 32;
    gload16(gAh + k0, Ash + w * 512);
    gload16(gAl + k0, Asl + w * 512);
    const unsigned short* gBh = W1h + ((size_t)(t * 4 + w) * MLP + lane) * 8;
    const unsigned short* gBl = W1l + ((size_t)(t * 4 + w) * MLP + lane) * 8;
    gload16(gBh, Bsh + w * 1024);
    gload16(gBh + 64 * 8, Bsh + w * 1024 + 64 * 8);
    gload16(gBl, Bsl + w * 1024);
    gload16(gBl + 64 * 8, Bsl + w * 1024 + 64 * 8);
    __syncthreads();
    bf16x8 bh[4], bl[4];
#pragma unroll
    for (int fj = 0; fj < 4; ++fj) {
      bh[fj] = *reinterpret_cast<const bf16x8*>(Bsh + lk * 1024 + (c0w + fj * 16 + lrow) * 8);
      bl[fj] = *reinterpret_cast<const bf16x8*>(Bsl + lk * 1024 + (c0w + fj * 16 + lrow) * 8);
    }
#pragma unroll
    for (int fi = 0; fi < 2; ++fi) {
      bf16x8 ah = *reinterpret_cast<const bf16x8*>(Ash + lk * 512 + (r0w + fi * 16 + lrow) * 8);
      bf16x8 al = *reinterpret_cast<const bf16x8*>(Asl + lk * 512 + (r0w + fi * 16 + lrow) * 8);
#pragma unroll
      for (int fj = 0; fj < 4; ++fj) {
        acc1[fi][fj] = __builtin_amdgcn_mfma_f32_16x16x32_bf16(ah, bh[fj], acc1[fi][fj], 0, 0, 0);
        acc1[fi][fj] = __builtin_amdgcn_mfma_f32_16x16x32_bf16(ah, bl[fj], acc1[fi][fj], 0, 0, 0);
        acc1[fi][fj] = __builtin_amdgcn_mfma_f32_16x16x32_bf16(al, bh[fj], acc1[fi][fj], 0, 0, 0);
      }
    }
    __syncthreads();
  }

#pragma unroll
  for (int fi = 0; fi < 2; ++fi) {
#pragma unroll
    for (int r2 = 0; r2 < 4; ++r2) {
      int row = r0w + fi * 16 + lk * 4 + r2;
#pragma unroll
      for (int fj = 0; fj < 4; ++fj) {
        int col = c0w + fj * 16 + lrow;
        float v = acc1[fi][fj][r2] + bias1[col];
        float gl = 0.5f * v * (1.0f + erff(v * 0.70710678118654752f));
        unsigned short hi, lo;
        split_bf(gl, hi, lo);
        int o = (col >> 3) * 512 + row * 8 + (col & 7);
        Am_h[o] = hi;
        Am_l[o] = lo;
      }
    }
  }
  __syncthreads();

  f32x4 acc2[2][8];
#pragma unroll
  for (int i = 0; i < 2; ++i)
#pragma unroll
    for (int j = 0; j < 8; ++j) acc2[i][j] = (f32x4){0.f, 0.f, 0.f, 0.f};
  int c0w2 = wc * 128;

#pragma unroll
  for (int t = 0; t < 4; ++t) {
    const unsigned short* gBh = W2h + ((size_t)(t * 4 + w) * CH + lane) * 8;
    const unsigned short* gBl = W2l + ((size_t)(t * 4 + w) * CH + lane) * 8;
#pragma unroll
    for (int s = 0; s < 4; ++s) {
      gload16(gBh + s * 64 * 8, B2h + w * 2048 + s * 64 * 8);
      gload16(gBl + s * 64 * 8, B2l + w * 2048 + s * 64 * 8);
    }
    __syncthreads();
    bf16x8 bh[8], bl[8];
#pragma unroll
    for (int fj = 0; fj < 8; ++fj) {
      bh[fj] = *reinterpret_cast<const bf16x8*>(B2h + lk * 2048 + (c0w2 + fj * 16 + lrow) * 8);
      bl[fj] = *reinterpret_cast<const bf16x8*>(B2l + lk * 2048 + (c0w2 + fj * 16 + lrow) * 8);
    }
#pragma unroll
    for (int fi = 0; fi < 2; ++fi) {
      bf16x8 ah = *reinterpret_cast<const bf16x8*>(Am_h + (t * 4 + lk) * 512 + (r0w + fi * 16 + lrow) * 8);
      bf16x8 al = *reinterpret_cast<const bf16x8*>(Am_l + (t * 4 + lk) * 512 + (r0w + fi * 16 + lrow) * 8);
#pragma unroll
      for (int fj = 0; fj < 8; ++fj) {
        acc2[fi][fj] = __builtin_amdgcn_mfma_f32_16x16x32_bf16(ah, bh[fj], acc2[fi][fj], 0, 0, 0);
        acc2[fi][fj] = __builtin_amdgcn_mfma_f32_16x16x32_bf16(ah, bl[fj], acc2[fi][fj], 0, 0, 0);
        acc2[fi][fj] = __builtin_amdgcn_mfma_f32_16x16x32_bf16(al, bh[fj], acc2[fi][fj], 0, 0, 0);
      }
    }
    __syncthreads();
  }

#pragma unroll
  for (int fi = 0; fi < 2; ++fi) {
#pragma unroll
    for (int r2 = 0; r2 < 4; ++r2) {
      int row_l = r0w + fi * 16 + lk * 4 + r2;
      if (row_l >= rows) continue;
      int rg = row0 + row_l;
      int s = rg / HW, p = rg - s * HW;
      int bsrt = perm[s];
      size_t gxb = ((size_t)bsrt * HW + p) * CH;
      float wr_ = wgt[bsrt];
#pragma unroll
      for (int fj = 0; fj < 8; ++fj) {
        int ocol = c0w2 + fj * 16 + lrow;
        float vv = (acc2[fi][fj][r2] + bias2[ocol] + X[gxb + ocol]) * wr_;
        X[gxb + ocol] = vv;
        Oout[gxb + ocol] = vv;
      }
    }
  }
}

// ---------------------------------------------------------------------------
// Row-local attention; float4-vectorized staging (round-20 proven).
__global__ __launch_bounds__(256) void attn_kernel(
    const float* __restrict__ q, const float* __restrict__ k,
    const float* __restrict__ v, unsigned short* __restrict__ ohi,
    unsigned short* __restrict__ olo) {
  int br = blockIdx.x;  // sorted_batch*14 + row
  int b = br / ROWLEN, row = br % ROWLEN;
  size_t base = ((size_t)b * HW + (size_t)row * ROWLEN) * CH;
  __shared__ float qs[ROWLEN][CH + 4];
  __shared__ float ks[ROWLEN][CH + 4];
  __shared__ float vs[ROWLEN][CH + 4];
  __shared__ float sc[4][ROWLEN][ROWLEN];
  int tid = threadIdx.x;  // 256
  for (int idx = tid; idx < ROWLEN * 64; idx += 256) {
    int rr = idx >> 6, c4 = (idx & 63) * 4;
    size_t go = base + (size_t)rr * CH + c4;
    float4 qv = *reinterpret_cast<const float4*>(&q[go]);
    float4 kv = *reinterpret_cast<const float4*>(&k[go]);
    float4 vv = *reinterpret_cast<const float4*>(&v[go]);
    *reinterpret_cast<float4*>(&qs[rr][c4]) = qv;
    *reinterpret_cast<float4*>(&ks[rr][c4]) = kv;
    *reinterpret_cast<float4*>(&vs[rr][c4]) = vv;
  }
  __syncthreads();
  for (int sidx = tid; sidx < 4 * ROWLEN * ROWLEN; sidx += 256) {
    int n = sidx / (ROWLEN * ROWLEN);
    int rem = sidx % (ROWLEN * ROWLEN);
    int i = rem / ROWLEN, j = rem % ROWLEN;
    const float* qp = &qs[i][n * 64];
    const float* kp = &ks[j][n * 64];
    float s = 0.f;
#pragma unroll
    for (int d = 0; d < 64; ++d) s = fmaf(qp[d], kp[d], s);
    sc[n][i][j] = s * 0.125f;
  }
  __syncthreads();
  if (tid < 4 * ROWLEN) {
    int n = tid / ROWLEN, i = tid % ROWLEN;
    float mx = sc[n][i][0];
    for (int j = 1; j < ROWLEN; ++j) mx = fmaxf(mx, sc[n][i][j]);
    float ex[ROWLEN]; float den = 0.f;
    for (int j = 0; j < ROWLEN; ++j) { ex[j] = expf(sc[n][i][j] - mx); den += ex[j]; }
    float inv = 1.0f / den;
    for (int j = 0; j < ROWLEN; ++j) sc[n][i][j] = ex[j] * inv;
  }
  __syncthreads();
  int n = tid / 64;
  for (int i = 0; i < ROWLEN; ++i) {
    float s = 0.f;
#pragma unroll
    for (int j = 0; j < ROWLEN; ++j) s = fmaf(sc[n][i][j], vs[j][tid], s);
    unsigned short hi, lo;
    split_bf(s, hi, lo);
    ohi[base + (size_t)i * CH + tid] = hi;
    olo[base + (size_t)i * CH + tid] = lo;
  }
}

// ---------------------------------------------------------------------------
extern "C" void kernel_launch(void* const* d_in, const int* in_sizes, int n_in,
                              void* d_out, int out_size, void* d_ws, size_t ws_size,
                              hipStream_t stream) {
  const float* stem = (const float*)d_in[0];
  const float* gate_w = (const float*)d_in[1];
  const float* gate_b = (const float*)d_in[2];
  const float* ln1_g = (const float*)d_in[3];
  const float* ln1_b = (const float*)d_in[4];
  const float* wq = (const float*)d_in[5];
  const float* bq = (const float*)d_in[6];
  const float* wk = (const float*)d_in[7];
  const float* bk = (const float*)d_in[8];
  const float* wv = (const float*)d_in[9];
  const float* bv = (const float*)d_in[10];
  const float* wo = (const float*)d_in[11];
  const float* bo = (const float*)d_in[12];
  const float* ln2_g = (const float*)d_in[13];
  const float* ln2_b = (const float*)d_in[14];
  const float* w1 = (const float*)d_in[15];
  const float* b1 = (const float*)d_in[16];
  const float* w2 = (const float*)d_in[17];
  const float* b2 = (const float*)d_in[18];

  float* out = (float*)d_out;
  float* ws = (float*)d_ws;
  const size_t IMG = (size_t)BNUM * HW * CH;  // 6,422,528 floats
  float* x = ws;                                       // fp32 residual
  unsigned short* h_hi = (unsigned short*)(ws + IMG);
  unsigned short* h_lo = h_hi + (size_t)MTOT * CH;
  float* q = ws + 2 * IMG;
  float* k = ws + 3 * IMG;
  float* v = ws + 4 * IMG;
  float* psum = q;   // router partials (BNUM*RSLICE*CH floats); q dead then
  float* weight = ws + 5 * IMG;
  int* ip = (int*)(weight + BNUM);
  int* eidx = ip;              ip += BNUM;
  int* perm = ip;              ip += BNUM;
  int* te128 = ip;             ip += MAXT128;
  int* tr0128 = ip;            ip += MAXT128;
  int* trw128 = ip;            ip += MAXT128;
  int* te64 = ip;              ip += MAXT64;
  int* tr064 = ip;             ip += MAXT64;
  int* trw64 = ip;             ip += MAXT64;
  int* rcnt = ip;              ip += 4;
  unsigned short* Whi_p = (unsigned short*)(ws + 5 * IMG + 4096);

  // all-layer prepack if workspace allows (needs ~191.4 MB), else per-layer.
  const size_t base_bytes = (5 * IMG + 4096) * sizeof(float);
  const int all_mode = (ws_size >= base_bytes + (size_t)4 * PK_TOTAL * 2 * sizeof(unsigned short)) ? 1 : 0;
  const int nplane = all_mode ? LNUM : 1;
  unsigned short* Wlo_p = Whi_p + (size_t)nplane * PK_TOTAL;

  float* probs_out = out + 4 * IMG;
  float* idx_out = probs_out + (size_t)LNUM * BNUM * ENUM;

  transpose_stem<<<dim3(8, 7, BNUM), dim3(32, 8), 0, stream>>>(stem, x, rcnt);
  if (all_mode) {
    prepack<<<dim3(32, 6, ENUM * LNUM), 256, 0, stream>>>(
        wq, wk, wv, wo, w1, w2, Whi_p, Wlo_p, 0, PK_TOTAL);
  }

  for (int li = 0; li < LNUM; ++li) {
    router_mean<<<BNUM * RSLICE, 256, 0, stream>>>(x, psum);
    router_finish<<<BNUM, 256, 0, stream>>>(
        psum, gate_w, gate_b, probs_out, idx_out, weight, eidx, rcnt, perm,
        te128, tr0128, trw128, te64, tr064, trw64, li);
    if (!all_mode) {
      prepack<<<dim3(32, 6, ENUM), 256, 0, stream>>>(
          wq, wk, wv, wo, w1, w2, Whi_p, Wlo_p, li, 0);
    }
    size_t plane = all_mode ? (size_t)li * PK_TOTAL : 0;
    ln_kernel<<<MTOT / 4, 256, 0, stream>>>(x, h_hi, h_lo, ln1_g, ln1_b, eidx, perm, li);
    gemm_mfma<0, 256, 256, 6, 128, MAXT128><<<dim3(6 * MAXT128), 256, 0, stream>>>(
        h_hi, h_lo, Whi_p, Wlo_p, plane + PK_WQ, (size_t)(ENUM * CH * CH),
        bq, bk, bv, q, k, v, nullptr,
        te128, tr0128, trw128, perm, li);
    attn_kernel<<<BNUM * ROWLEN, 256, 0, stream>>>(q, k, v, h_hi, h_lo);
    gemm_mfma<2, 256, 256, 2, 64, MAXT64><<<dim3(2 * MAXT64), 256, 0, stream>>>(
        h_hi, h_lo, Whi_p, Wlo_p, plane + PK_WO, 0,
        bo, nullptr, nullptr, nullptr, nullptr, nullptr,
        x, te64, tr064, trw64, perm, li);
    ln_kernel<<<MTOT / 4, 256, 0, stream>>>(x, h_hi, h_lo, ln2_g, ln2_b, eidx, perm, li);
    fused_mlp<<<dim3(MAXT64), 256, 0, stream>>>(
        h_hi, h_lo, Whi_p, Wlo_p, plane, b1, b2, out + (size_t)li * IMG,
        x, weight, te64, tr064, trw64, perm, li);
  }
}

// Round 29
// 840.475 us; speedup vs baseline: 1.0121x; 1.0121x over previous
//
#include <hip/hip_runtime.h>
#include <hip/hip_bf16.h>

#define LNUM 4
#define ENUM 12
#define CH 256
#define MLP 128
#define HW 196
#define BNUM 128
#define ROWLEN 14
#define MTOT (BNUM * HW)   // 25088 rows
#define MAXT128 208        // TM=128 tiles: 196 full + <=12 partial
#define MAXT64 416         // TM=64 tiles: 392 full + <=12 partial

// packed per-layer weight plane offsets (ushort elements)
#define PK_WQ 0
#define PK_WK 786432
#define PK_WV 1572864
#define PK_WO 2359296
#define PK_W1 3145728
#define PK_W2 3538944
#define PK_TOTAL 3932160

using bf16x8 = __attribute__((ext_vector_type(8))) short;
using f32x4 = __attribute__((ext_vector_type(4))) float;

__device__ inline unsigned short f2bf(float v) {
  __hip_bfloat16 b = __float2bfloat16(v);   // RNE
  return *reinterpret_cast<unsigned short*>(&b);
}
__device__ inline float bf2f(unsigned short u) {
  union { unsigned int i; float f; } cv;
  cv.i = ((unsigned int)u) << 16;
  return cv.f;
}
__device__ inline void split_bf(float v, unsigned short& hi, unsigned short& lo) {
  hi = f2bf(v);
  lo = f2bf(v - bf2f(hi));
}
// async global->LDS 16B per lane; dest = uniform base + lane*16; src per-lane
__device__ inline void gload16(const void* g, void* l) {
  __builtin_amdgcn_global_load_lds(
      (const __attribute__((address_space(1))) unsigned int*)g,
      (__attribute__((address_space(3))) unsigned int*)l, 16, 0, 0);
}

// ---------------------------------------------------------------------------
__global__ __launch_bounds__(256) void transpose_stem(const float* __restrict__ stem,
                                                      float* __restrict__ x,
                                                      int* __restrict__ rcnt) {
  if (blockIdx.x == 0 && blockIdx.y == 0 && blockIdx.z == 0 &&
      threadIdx.x == 0 && threadIdx.y == 0)
    rcnt[0] = 0;
  __shared__ float tile[32][33];
  int b = blockIdx.z;
  int c0 = blockIdx.x * 32;
  int p0 = blockIdx.y * 32;
  int tx = threadIdx.x;
  int ty = threadIdx.y;
  for (int i = ty; i < 32; i += 8) {
    int c = c0 + i, p = p0 + tx;
    if (p < HW) tile[i][tx] = stem[(size_t)b * CH * HW + (size_t)c * HW + p];
  }
  __syncthreads();
  for (int i = ty; i < 32; i += 8) {
    int p = p0 + i, c = c0 + tx;
    if (p < HW) x[(size_t)b * HW * CH + (size_t)p * CH + c] = tile[tx][i];
  }
}

// ---------------------------------------------------------------------------
// Router fused with route_plan. Mean-pool: 4 waves x 49 rows with EXPLICIT
// 7-deep load batching. Accumulation order unchanged -> bit-identical.
// Last block (device-scope atomic) builds both tile tables and resets rcnt.
__global__ __launch_bounds__(256) void router_kernel(
    const float* __restrict__ x, const float* __restrict__ gate_w,
    const float* __restrict__ gate_b, float* __restrict__ probs_out,
    float* __restrict__ idx_out, float* __restrict__ weight,
    int* __restrict__ eidx, int* __restrict__ rcnt, int* __restrict__ perm,
    int* __restrict__ te128, int* __restrict__ tr0128, int* __restrict__ trw128,
    int* __restrict__ te64, int* __restrict__ tr064, int* __restrict__ trw64,
    int li) {
  int b = blockIdx.x;
  int tid = threadIdx.x;
  int w = tid >> 6, lane = tid & 63;
  const float* xb = x + (size_t)b * HW * CH;
  float a0 = 0.f, a1 = 0.f, a2 = 0.f, a3 = 0.f;
  int p0 = w * 49;
#pragma unroll
  for (int g = 0; g < 7; ++g) {
    float4 t[7];
#pragma unroll
    for (int i = 0; i < 7; ++i)
      t[i] = *reinterpret_cast<const float4*>(
          &xb[(size_t)(p0 + g * 7 + i) * CH + lane * 4]);
#pragma unroll
    for (int i = 0; i < 7; ++i) {
      a0 += t[i].x; a1 += t[i].y; a2 += t[i].z; a3 += t[i].w;
    }
  }
  __shared__ float rsum[4][CH];
  rsum[w][lane * 4 + 0] = a0;
  rsum[w][lane * 4 + 1] = a1;
  rsum[w][lane * 4 + 2] = a2;
  rsum[w][lane * 4 + 3] = a3;
  __syncthreads();
  __shared__ float r[CH];
  r[tid] = (rsum[0][tid] + rsum[1][tid] + rsum[2][tid] + rsum[3][tid]) *
           (1.0f / (float)HW);
  __syncthreads();
  __shared__ float part[ENUM][16];
  if (tid < 192) {
    int e = tid >> 4, seg = tid & 15;
    const float* gw = gate_w + (size_t)li * CH * ENUM;
    float acc = 0.f;
#pragma unroll
    for (int kk = 0; kk < 16; ++kk) {
      int k = seg * 16 + kk;
      acc += r[k] * gw[(size_t)k * ENUM + e];
    }
    part[e][seg] = acc;
  }
  __syncthreads();
  __shared__ float logits[ENUM];
  if (tid < ENUM) {
    float acc = gate_b[li * ENUM + tid];
#pragma unroll
    for (int seg = 0; seg < 16; ++seg) acc += part[tid][seg];
    logits[tid] = acc;
  }
  __syncthreads();
  __shared__ int last;
  if (tid == 0) {
    float mx = logits[0]; int am = 0;
    for (int e = 1; e < ENUM; ++e) if (logits[e] > mx) { mx = logits[e]; am = e; }
    float pr[ENUM]; float den = 0.f;
    for (int e = 0; e < ENUM; ++e) { pr[e] = expf(logits[e] - mx); den += pr[e]; }
    float inv = 1.0f / den;
    for (int e = 0; e < ENUM; ++e) pr[e] *= inv;
    for (int e = 0; e < ENUM; ++e)
      probs_out[(size_t)(li * BNUM + b) * ENUM + e] = pr[e];
    idx_out[li * BNUM + b] = (float)am;
    float pmax = pr[am];
    weight[b] = pmax / (pmax + 1e-8f);
    eidx[b] = am;
    __threadfence();                       // release eidx before counting in
    int old = atomicAdd(rcnt, 1);
    last = (old == BNUM - 1) ? 1 : 0;
  }
  __syncthreads();
  if (!last) return;
  __threadfence();                         // acquire: see all blocks' eidx
  __shared__ int cnt[ENUM], start[ENUM];
  int t = tid;
  if (t < ENUM) {
    int cc = 0;
    for (int bb = 0; bb < BNUM; ++bb) if (eidx[bb] == t) ++cc;
    cnt[t] = cc;
  }
  __syncthreads();
  if (t == 0) {
    int ss = 0;
    for (int e = 0; e < ENUM; ++e) { start[e] = ss; ss += cnt[e]; }
  }
  __syncthreads();
  if (t < ENUM) {
    int pos = start[t];
    for (int bb = 0; bb < BNUM; ++bb) if (eidx[bb] == t) perm[pos++] = bb;
  }
  if (t == 0) {
    int tile = 0;
    for (int e = 0; e < ENUM; ++e) {
      int rows = cnt[e] * HW;
      int row0 = start[e] * HW;
      int off = 0;
      while (off < rows) {
        te128[tile] = e;
        tr0128[tile] = row0 + off;
        int rem = rows - off;
        trw128[tile] = rem < 128 ? rem : 128;
        ++tile; off += 128;
      }
    }
    for (; tile < MAXT128; ++tile) { trw128[tile] = 0; te128[tile] = 0; tr0128[tile] = 0; }
    rcnt[0] = 0;                           // reset for next layer
  } else if (t == 1) {
    int tile = 0;
    for (int e = 0; e < ENUM; ++e) {
      int rows = cnt[e] * HW;
      int row0 = start[e] * HW;
      int off = 0;
      while (off < rows) {
        te64[tile] = e;
        tr064[tile] = row0 + off;
        int rem = rows - off;
        trw64[tile] = rem < 64 ? rem : 64;
        ++tile; off += 64;
      }
    }
    for (; tile < MAXT64; ++tile) { trw64[tile] = 0; te64[tile] = 0; tr064[tile] = 0; }
  }
}

// ---------------------------------------------------------------------------
// Pre-split + pre-pack weights: [K/8][N][8] bf16 hi/lo per (layer, expert).
__global__ __launch_bounds__(256) void prepack(
    const float* __restrict__ wq, const float* __restrict__ wk,
    const float* __restrict__ wv, const float* __restrict__ wo,
    const float* __restrict__ w1, const float* __restrict__ w2,
    unsigned short* __restrict__ Phi, unsigned short* __restrict__ Plo,
    int li0, int plane_mult) {
  int lz = blockIdx.z / ENUM;
  int e = blockIdx.z % ENUM;
  int li = li0 + lz;
  size_t plane = (size_t)lz * plane_mult;
  int ts = blockIdx.y;    // 6
  int K = (ts == 5) ? 128 : 256;
  int N = (ts == 4) ? 128 : 256;
  int total = (K / 8) * N;
  int id = blockIdx.x * 256 + threadIdx.x;
  if (id >= total) return;
  const float* src;
  size_t dst0;
  switch (ts) {
    case 0: src = wq; dst0 = PK_WQ; break;
    case 1: src = wk; dst0 = PK_WK; break;
    case 2: src = wv; dst0 = PK_WV; break;
    case 3: src = wo; dst0 = PK_WO; break;
    case 4: src = w1; dst0 = PK_W1; break;
    default: src = w2; dst0 = PK_W2; break;
  }
  src += ((size_t)li * ENUM + e) * K * N;
  size_t dst = plane + dst0 + (size_t)e * K * N;
  int n = id % N;
  int kg = id / N;
  const float* sp = src + (size_t)kg * 8 * N + n;
  unsigned short hs[8], ls[8];
#pragma unroll
  for (int j = 0; j < 8; ++j) split_bf(sp[(size_t)j * N], hs[j], ls[j]);
  uint4 ph, pl;
  ph.x = hs[0] | ((unsigned)hs[1] << 16); ph.y = hs[2] | ((unsigned)hs[3] << 16);
  ph.z = hs[4] | ((unsigned)hs[5] << 16); ph.w = hs[6] | ((unsigned)hs[7] << 16);
  pl.x = ls[0] | ((unsigned)ls[1] << 16); pl.y = ls[2] | ((unsigned)ls[3] << 16);
  pl.z = ls[4] | ((unsigned)ls[5] << 16); pl.w = ls[6] | ((unsigned)ls[7] << 16);
  size_t o = dst + (size_t)(kg * N + n) * 8;
  *reinterpret_cast<uint4*>(Phi + o) = ph;
  *reinterpret_cast<uint4*>(Plo + o) = pl;
}

// ---------------------------------------------------------------------------
// LayerNorm: one WAVE per token (4 tokens/block), no barriers, vectorized.
__global__ __launch_bounds__(256) void ln_kernel(
    const float* __restrict__ xin, unsigned short* __restrict__ hhi,
    unsigned short* __restrict__ hlo,
    const float* __restrict__ g, const float* __restrict__ bta,
    const int* __restrict__ eidx, const int* __restrict__ perm, int li) {
  int tok = blockIdx.x * 4 + (threadIdx.x >> 6);   // sorted token id
  int lane = threadIdx.x & 63;
  int s = tok / HW, p = tok - s * HW;
  int b = perm[s];
  int e = eidx[b];
  float4 vx = *reinterpret_cast<const float4*>(
      &xin[((size_t)b * HW + p) * CH + lane * 4]);
  float sm = vx.x + vx.y + vx.z + vx.w;
#pragma unroll
  for (int off = 1; off < 64; off <<= 1) sm += __shfl_xor(sm, off, 64);
  float mu = sm * (1.0f / (float)CH);
  float d0 = vx.x - mu, d1 = vx.y - mu, d2 = vx.z - mu, d3 = vx.w - mu;
  float s2 = d0 * d0 + d1 * d1 + d2 * d2 + d3 * d3;
#pragma unroll
  for (int off = 1; off < 64; off <<= 1) s2 += __shfl_xor(s2, off, 64);
  float rs = rsqrtf(s2 * (1.0f / (float)CH) + 1e-5f);
  size_t gb = ((size_t)li * ENUM + e) * CH + lane * 4;
  float4 gg = *reinterpret_cast<const float4*>(&g[gb]);
  float4 bb = *reinterpret_cast<const float4*>(&bta[gb]);
  float h0 = d0 * rs * gg.x + bb.x;
  float h1 = d1 * rs * gg.y + bb.y;
  float h2 = d2 * rs * gg.z + bb.z;
  float h3 = d3 * rs * gg.w + bb.w;
  ushort4 vh, vl;
  split_bf(h0, vh.x, vl.x);
  split_bf(h1, vh.y, vl.y);
  split_bf(h2, vh.z, vl.z);
  split_bf(h3, vh.w, vl.w);
  size_t ob = (size_t)tok * CH + lane * 4;
  *reinterpret_cast<ushort4*>(&hhi[ob]) = vh;
  *reinterpret_cast<ushort4*>(&hlo[ob]) = vl;
}

// ---------------------------------------------------------------------------
// Split-bf16 MFMA grouped GEMM, TM_ x 128 tile, async LDS stage, single buf,
// 2 barriers / K-step, XCD-chunked bijective block swizzle. (round-13 proven)
// EPI: 0 QKV fp32 store | 2 +X via perm
template <int EPI, int NT, int KDIM, int NXTOT, int TM_, int NTILE>
__global__ __launch_bounds__(256) void gemm_mfma(
    const unsigned short* __restrict__ Ahi, const unsigned short* __restrict__ Alo,
    const unsigned short* __restrict__ Whi, const unsigned short* __restrict__ Wlo,
    size_t wbase, size_t wstride,
    const float* __restrict__ B0, const float* __restrict__ B1p, const float* __restrict__ B2p,
    float* __restrict__ O0, float* __restrict__ O1p, float* __restrict__ O2p,
    float* __restrict__ X,
    const int* __restrict__ tile_e, const int* __restrict__ tile_row0,
    const int* __restrict__ tile_rows, const int* __restrict__ perm, int li) {
  constexpr int NX = NT / 128;
  constexpr int NSTEP = KDIM / 32;
  constexpr int FM = TM_ / 32;
  constexpr int NSEG = TM_ / 64;
  int nwg = NXTOT * NTILE;
  int orig = blockIdx.x;
  int q = nwg >> 3, r = nwg & 7;
  int xcd = orig & 7, idx = orig >> 3;
  int wg = (xcd < r ? xcd * (q + 1) : r * (q + 1) + (xcd - r) * q) + idx;
  int tileid = wg / NXTOT;
  int cbx = wg % NXTOT;

  int rows = tile_rows[tileid];
  if (rows <= 0) return;
  int row0 = tile_row0[tileid];
  int e = tile_e[tileid];
  int cb = cbx / NX;
  int ncol0 = (cbx % NX) * 128;

  const float* Bt = (EPI == 0) ? (cb == 0 ? B0 : (cb == 1 ? B1p : B2p)) : B0;
  float* Oo = (EPI == 0) ? (cb == 0 ? O0 : (cb == 1 ? O1p : O2p)) : O0;
  size_t woff = wbase + (size_t)cb * wstride + (size_t)e * (KDIM * NT);
  const unsigned short* Wh = Whi + woff;
  const unsigned short* Wl = Wlo + woff;
  const float* bias = Bt + ((size_t)li * ENUM + e) * NT + ncol0;

  __shared__ unsigned short Ash[4][TM_][8], Asl[4][TM_][8];
  __shared__ unsigned short Bsh[4][128][8], Bsl[4][128][8];

  int tid = threadIdx.x;
  int lane = tid & 63, w = tid >> 6;
  int wr = w >> 1, wc = w & 1;
  int r0w = wr * (TM_ / 2), c0w = wc * 64;
  int lrow = lane & 15, lk = lane >> 4;

  const unsigned short* gAh[NSEG];
  const unsigned short* gAl[NSEG];
#pragma unroll
  for (int s = 0; s < NSEG; ++s) {
    int rl = (s * 64 + lane < rows) ? s * 64 + lane : 0;
    gAh[s] = Ahi + (size_t)(row0 + rl) * KDIM + w * 8;
    gAl[s] = Alo + (size_t)(row0 + rl) * KDIM + w * 8;
  }

  f32x4 acc[FM][4];
#pragma unroll
  for (int i = 0; i < FM; ++i)
#pragma unroll
    for (int j = 0; j < 4; ++j) acc[i][j] = (f32x4){0.f, 0.f, 0.f, 0.f};

#pragma unroll
  for (int t = 0; t < NSTEP; ++t) {
    int k0 = t * 32;
#pragma unroll
    for (int s = 0; s < NSEG; ++s) {
      gload16(gAh[s] + k0, &Ash[w][s * 64][0]);
      gload16(gAl[s] + k0, &Asl[w][s * 64][0]);
    }
    const unsigned short* gBh = Wh + ((size_t)(t * 4 + w) * NT + ncol0 + lane) * 8;
    const unsigned short* gBl = Wl + ((size_t)(t * 4 + w) * NT + ncol0 + lane) * 8;
    gload16(gBh, &Bsh[w][0][0]);
    gload16(gBh + 64 * 8, &Bsh[w][64][0]);
    gload16(gBl, &Bsl[w][0][0]);
    gload16(gBl + 64 * 8, &Bsl[w][64][0]);
    __syncthreads();
    bf16x8 bh[4], bl[4];
#pragma unroll
    for (int fj = 0; fj < 4; ++fj) {
      bh[fj] = *reinterpret_cast<const bf16x8*>(&Bsh[lk][c0w + fj * 16 + lrow][0]);
      bl[fj] = *reinterpret_cast<const bf16x8*>(&Bsl[lk][c0w + fj * 16 + lrow][0]);
    }
#pragma unroll
    for (int fi = 0; fi < FM; ++fi) {
      bf16x8 ah = *reinterpret_cast<const bf16x8*>(&Ash[lk][r0w + fi * 16 + lrow][0]);
      bf16x8 al = *reinterpret_cast<const bf16x8*>(&Asl[lk][r0w + fi * 16 + lrow][0]);
#pragma unroll
      for (int fj = 0; fj < 4; ++fj) {
        acc[fi][fj] = __builtin_amdgcn_mfma_f32_16x16x32_bf16(ah, bh[fj], acc[fi][fj], 0, 0, 0);
        acc[fi][fj] = __builtin_amdgcn_mfma_f32_16x16x32_bf16(ah, bl[fj], acc[fi][fj], 0, 0, 0);
        acc[fi][fj] = __builtin_amdgcn_mfma_f32_16x16x32_bf16(al, bh[fj], acc[fi][fj], 0, 0, 0);
      }
    }
    __syncthreads();
  }

#pragma unroll
  for (int fi = 0; fi < FM; ++fi) {
#pragma unroll
    for (int r2 = 0; r2 < 4; ++r2) {
      int row_l = r0w + fi * 16 + lk * 4 + r2;
      if (row_l >= rows) continue;
      int rg = row0 + row_l;
      size_t gxb = 0;
      if (EPI == 2) {
        int s = rg / HW, p = rg - s * HW;
        gxb = ((size_t)perm[s] * HW + p) * CH;
      }
#pragma unroll
      for (int fj = 0; fj < 4; ++fj) {
        int col = c0w + fj * 16 + lrow;
        int ocol = ncol0 + col;
        float v = acc[fi][fj][r2] + bias[col];
        if (EPI == 0) {
          Oo[(size_t)rg * NT + ocol] = v;
        } else {
          X[gxb + ocol] += v;
        }
      }
    }
  }
}

// ---------------------------------------------------------------------------
// Fused MLP: W1 GEMM (64x128, K=256) -> bias+GELU+split -> m-tile in LDS
// (W2 A-fragment layout) -> W2 GEMM (64x256, K=128) -> residual+scale+dual.
__global__ __launch_bounds__(256) void fused_mlp(
    const unsigned short* __restrict__ Ahi, const unsigned short* __restrict__ Alo,
    const unsigned short* __restrict__ Whi, const unsigned short* __restrict__ Wlo,
    size_t plane, const float* __restrict__ b1, const float* __restrict__ b2,
    float* __restrict__ Oout, float* __restrict__ X, const float* __restrict__ wgt,
    const int* __restrict__ tile_e, const int* __restrict__ tile_row0,
    const int* __restrict__ tile_rows, const int* __restrict__ perm, int li) {
  int nwg = MAXT64;
  int orig = blockIdx.x;
  int q = nwg >> 3, r = nwg & 7;
  int xcd = orig & 7, idx = orig >> 3;
  int tileid = (xcd < r ? xcd * (q + 1) : r * (q + 1) + (xcd - r) * q) + idx;

  int rows = tile_rows[tileid];
  if (rows <= 0) return;
  int row0 = tile_row0[tileid];
  int e = tile_e[tileid];

  const unsigned short* W1h = Whi + plane + PK_W1 + (size_t)e * (CH * MLP);
  const unsigned short* W1l = Wlo + plane + PK_W1 + (size_t)e * (CH * MLP);
  const unsigned short* W2h = Whi + plane + PK_W2 + (size_t)e * (MLP * CH);
  const unsigned short* W2l = Wlo + plane + PK_W2 + (size_t)e * (MLP * CH);
  const float* bias1 = b1 + ((size_t)li * ENUM + e) * MLP;
  const float* bias2 = b2 + ((size_t)li * ENUM + e) * CH;

  __shared__ __align__(16) unsigned short smem[32768];
  unsigned short* Am_h = smem;                 // [16][64][8]
  unsigned short* Am_l = smem + 8192;
  unsigned short* S = smem + 16384;
  unsigned short* Ash = S;
  unsigned short* Asl = S + 2048;
  unsigned short* Bsh = S + 4096;
  unsigned short* Bsl = S + 8192;
  unsigned short* B2h = S;
  unsigned short* B2l = S + 8192;

  int tid = threadIdx.x;
  int lane = tid & 63, w = tid >> 6;
  int wr = w >> 1, wc = w & 1;
  int r0w = wr * 32, c0w = wc * 64;
  int lrow = lane & 15, lk = lane >> 4;

  int rl = (lane < rows) ? lane : 0;
  const unsigned short* gAh = Ahi + (size_t)(row0 + rl) * CH + w * 8;
  const unsigned short* gAl = Alo + (size_t)(row0 + rl) * CH + w * 8;

  f32x4 acc1[2][4];
#pragma unroll
  for (int i = 0; i < 2; ++i)
#pragma unroll
    for (int j = 0; j < 4; ++j) acc1[i][j] = (f32x4){0.f, 0.f, 0.f, 0.f};

#pragma unroll
  for (int t = 0; t < 8; ++t) {
    int k0 = t * 32;
    gload16(gAh + k0, Ash + w * 512);
    gload16(gAl + k0, Asl + w * 512);
    const unsigned short* gBh = W1h + ((size_t)(t * 4 + w) * MLP + lane) * 8;
    const unsigned short* gBl = W1l + ((size_t)(t * 4 + w) * MLP + lane) * 8;
    gload16(gBh, Bsh + w * 1024);
    gload16(gBh + 64 * 8, Bsh + w * 1024 + 64 * 8);
    gload16(gBl, Bsl + w * 1024);
    gload16(gBl + 64 * 8, Bsl + w * 1024 + 64 * 8);
    __syncthreads();
    bf16x8 bh[4], bl[4];
#pragma unroll
    for (int fj = 0; fj < 4; ++fj) {
      bh[fj] = *reinterpret_cast<const bf16x8*>(Bsh + lk * 1024 + (c0w + fj * 16 + lrow) * 8);
      bl[fj] = *reinterpret_cast<const bf16x8*>(Bsl + lk * 1024 + (c0w + fj * 16 + lrow) * 8);
    }
#pragma unroll
    for (int fi = 0; fi < 2; ++fi) {
      bf16x8 ah = *reinterpret_cast<const bf16x8*>(Ash + lk * 512 + (r0w + fi * 16 + lrow) * 8);
      bf16x8 al = *reinterpret_cast<const bf16x8*>(Asl + lk * 512 + (r0w + fi * 16 + lrow) * 8);
#pragma unroll
      for (int fj = 0; fj < 4; ++fj) {
        acc1[fi][fj] = __builtin_amdgcn_mfma_f32_16x16x32_bf16(ah, bh[fj], acc1[fi][fj], 0, 0, 0);
        acc1[fi][fj] = __builtin_amdgcn_mfma_f32_16x16x32_bf16(ah, bl[fj], acc1[fi][fj], 0, 0, 0);
        acc1[fi][fj] = __builtin_amdgcn_mfma_f32_16x16x32_bf16(al, bh[fj], acc1[fi][fj], 0, 0, 0);
      }
    }
    __syncthreads();
  }

#pragma unroll
  for (int fi = 0; fi < 2; ++fi) {
#pragma unroll
    for (int r2 = 0; r2 < 4; ++r2) {
      int row = r0w + fi * 16 + lk * 4 + r2;
#pragma unroll
      for (int fj = 0; fj < 4; ++fj) {
        int col = c0w + fj * 16 + lrow;
        float v = acc1[fi][fj][r2] + bias1[col];
        float gl = 0.5f * v * (1.0f + erff(v * 0.70710678118654752f));
        unsigned short hi, lo;
        split_bf(gl, hi, lo);
        int o = (col >> 3) * 512 + row * 8 + (col & 7);
        Am_h[o] = hi;
        Am_l[o] = lo;
      }
    }
  }
  __syncthreads();

  f32x4 acc2[2][8];
#pragma unroll
  for (int i = 0; i < 2; ++i)
#pragma unroll
    for (int j = 0; j < 8; ++j) acc2[i][j] = (f32x4){0.f, 0.f, 0.f, 0.f};
  int c0w2 = wc * 128;

#pragma unroll
  for (int t = 0; t < 4; ++t) {
    const unsigned short* gBh = W2h + ((size_t)(t * 4 + w) * CH + lane) * 8;
    const unsigned short* gBl = W2l + ((size_t)(t * 4 + w) * CH + lane) * 8;
#pragma unroll
    for (int s = 0; s < 4; ++s) {
      gload16(gBh + s * 64 * 8, B2h + w * 2048 + s * 64 * 8);
      gload16(gBl + s * 64 * 8, B2l + w * 2048 + s * 64 * 8);
    }
    __syncthreads();
    bf16x8 bh[8], bl[8];
#pragma unroll
    for (int fj = 0; fj < 8; ++fj) {
      bh[fj] = *reinterpret_cast<const bf16x8*>(B2h + lk * 2048 + (c0w2 + fj * 16 + lrow) * 8);
      bl[fj] = *reinterpret_cast<const bf16x8*>(B2l + lk * 2048 + (c0w2 + fj * 16 + lrow) * 8);
    }
#pragma unroll
    for (int fi = 0; fi < 2; ++fi) {
      bf16x8 ah = *reinterpret_cast<const bf16x8*>(Am_h + (t * 4 + lk) * 512 + (r0w + fi * 16 + lrow) * 8);
      bf16x8 al = *reinterpret_cast<const bf16x8*>(Am_l + (t * 4 + lk) * 512 + (r0w + fi * 16 + lrow) * 8);
#pragma unroll
      for (int fj = 0; fj < 8; ++fj) {
        acc2[fi][fj] = __builtin_amdgcn_mfma_f32_16x16x32_bf16(ah, bh[fj], acc2[fi][fj], 0, 0, 0);
        acc2[fi][fj] = __builtin_amdgcn_mfma_f32_16x16x32_bf16(ah, bl[fj], acc2[fi][fj], 0, 0, 0);
        acc2[fi][fj] = __builtin_amdgcn_mfma_f32_16x16x32_bf16(al, bh[fj], acc2[fi][fj], 0, 0, 0);
      }
    }
    __syncthreads();
  }

#pragma unroll
  for (int fi = 0; fi < 2; ++fi) {
#pragma unroll
    for (int r2 = 0; r2 < 4; ++r2) {
      int row_l = r0w + fi * 16 + lk * 4 + r2;
      if (row_l >= rows) continue;
      int rg = row0 + row_l;
      int s = rg / HW, p = rg - s * HW;
      int bsrt = perm[s];
      size_t gxb = ((size_t)bsrt * HW + p) * CH;
      float wr_ = wgt[bsrt];
#pragma unroll
      for (int fj = 0; fj < 8; ++fj) {
        int ocol = c0w2 + fj * 16 + lrow;
        float vv = (acc2[fi][fj][r2] + bias2[ocol] + X[gxb + ocol]) * wr_;
        X[gxb + ocol] = vv;
        Oout[gxb + ocol] = vv;
      }
    }
  }
}

// ---------------------------------------------------------------------------
// Row-local attention; float4-vectorized staging (round-20 proven).
__global__ __launch_bounds__(256) void attn_kernel(
    const float* __restrict__ q, const float* __restrict__ k,
    const float* __restrict__ v, unsigned short* __restrict__ ohi,
    unsigned short* __restrict__ olo) {
  int br = blockIdx.x;  // sorted_batch*14 + row
  int b = br / ROWLEN, row = br % ROWLEN;
  size_t base = ((size_t)b * HW + (size_t)row * ROWLEN) * CH;
  __shared__ float qs[ROWLEN][CH + 4];
  __shared__ float ks[ROWLEN][CH + 4];
  __shared__ float vs[ROWLEN][CH + 4];
  __shared__ float sc[4][ROWLEN][ROWLEN];
  int tid = threadIdx.x;  // 256
  for (int idx = tid; idx < ROWLEN * 64; idx += 256) {
    int rr = idx >> 6, c4 = (idx & 63) * 4;
    size_t go = base + (size_t)rr * CH + c4;
    float4 qv = *reinterpret_cast<const float4*>(&q[go]);
    float4 kv = *reinterpret_cast<const float4*>(&k[go]);
    float4 vv = *reinterpret_cast<const float4*>(&v[go]);
    *reinterpret_cast<float4*>(&qs[rr][c4]) = qv;
    *reinterpret_cast<float4*>(&ks[rr][c4]) = kv;
    *reinterpret_cast<float4*>(&vs[rr][c4]) = vv;
  }
  __syncthreads();
  for (int sidx = tid; sidx < 4 * ROWLEN * ROWLEN; sidx += 256) {
    int n = sidx / (ROWLEN * ROWLEN);
    int rem = sidx % (ROWLEN * ROWLEN);
    int i = rem / ROWLEN, j = rem % ROWLEN;
    const float* qp = &qs[i][n * 64];
    const float* kp = &ks[j][n * 64];
    float s = 0.f;
#pragma unroll
    for (int d = 0; d < 64; ++d) s = fmaf(qp[d], kp[d], s);
    sc[n][i][j] = s * 0.125f;
  }
  __syncthreads();
  if (tid < 4 * ROWLEN) {
    int n = tid / ROWLEN, i = tid % ROWLEN;
    float mx = sc[n][i][0];
    for (int j = 1; j < ROWLEN; ++j) mx = fmaxf(mx, sc[n][i][j]);
    float ex[ROWLEN]; float den = 0.f;
    for (int j = 0; j < ROWLEN; ++j) { ex[j] = expf(sc[n][i][j] - mx); den += ex[j]; }
    float inv = 1.0f / den;
    for (int j = 0; j < ROWLEN; ++j) sc[n][i][j] = ex[j] * inv;
  }
  __syncthreads();
  int n = tid / 64;
  for (int i = 0; i < ROWLEN; ++i) {
    float s = 0.f;
#pragma unroll
    for (int j = 0; j < ROWLEN; ++j) s = fmaf(sc[n][i][j], vs[j][tid], s);
    unsigned short hi, lo;
    split_bf(s, hi, lo);
    ohi[base + (size_t)i * CH + tid] = hi;
    olo[base + (size_t)i * CH + tid] = lo;
  }
}

// ---------------------------------------------------------------------------
extern "C" void kernel_launch(void* const* d_in, const int* in_sizes, int n_in,
                              void* d_out, int out_size, void* d_ws, size_t ws_size,
                              hipStream_t stream) {
  const float* stem = (const float*)d_in[0];
  const float* gate_w = (const float*)d_in[1];
  const float* gate_b = (const float*)d_in[2];
  const float* ln1_g = (const float*)d_in[3];
  const float* ln1_b = (const float*)d_in[4];
  const float* wq = (const float*)d_in[5];
  const float* bq = (const float*)d_in[6];
  const float* wk = (const float*)d_in[7];
  const float* bk = (const float*)d_in[8];
  const float* wv = (const float*)d_in[9];
  const float* bv = (const float*)d_in[10];
  const float* wo = (const float*)d_in[11];
  const float* bo = (const float*)d_in[12];
  const float* ln2_g = (const float*)d_in[13];
  const float* ln2_b = (const float*)d_in[14];
  const float* w1 = (const float*)d_in[15];
  const float* b1 = (const float*)d_in[16];
  const float* w2 = (const float*)d_in[17];
  const float* b2 = (const float*)d_in[18];

  float* out = (float*)d_out;
  float* ws = (float*)d_ws;
  const size_t IMG = (size_t)BNUM * HW * CH;  // 6,422,528 floats
  float* x = ws;                                       // fp32 residual
  unsigned short* h_hi = (unsigned short*)(ws + IMG);
  unsigned short* h_lo = h_hi + (size_t)MTOT * CH;
  float* q = ws + 2 * IMG;
  float* k = ws + 3 * IMG;
  float* v = ws + 4 * IMG;
  float* weight = ws + 5 * IMG;
  int* ip = (int*)(weight + BNUM);
  int* eidx = ip;              ip += BNUM;
  int* perm = ip;              ip += BNUM;
  int* te128 = ip;             ip += MAXT128;
  int* tr0128 = ip;            ip += MAXT128;
  int* trw128 = ip;            ip += MAXT128;
  int* te64 = ip;              ip += MAXT64;
  int* tr064 = ip;             ip += MAXT64;
  int* trw64 = ip;             ip += MAXT64;
  int* rcnt = ip;              ip += 4;
  unsigned short* Whi_p = (unsigned short*)(ws + 5 * IMG + 4096);

  // all-layer prepack if workspace allows (needs ~191.4 MB), else per-layer.
  const size_t base_bytes = (5 * IMG + 4096) * sizeof(float);
  const int all_mode = (ws_size >= base_bytes + (size_t)4 * PK_TOTAL * 2 * sizeof(unsigned short)) ? 1 : 0;
  const int nplane = all_mode ? LNUM : 1;
  unsigned short* Wlo_p = Whi_p + (size_t)nplane * PK_TOTAL;

  float* probs_out = out + 4 * IMG;
  float* idx_out = probs_out + (size_t)LNUM * BNUM * ENUM;

  transpose_stem<<<dim3(8, 7, BNUM), dim3(32, 8), 0, stream>>>(stem, x, rcnt);
  if (all_mode) {
    prepack<<<dim3(32, 6, ENUM * LNUM), 256, 0, stream>>>(
        wq, wk, wv, wo, w1, w2, Whi_p, Wlo_p, 0, PK_TOTAL);
  }

  for (int li = 0; li < LNUM; ++li) {
    router_kernel<<<BNUM, 256, 0, stream>>>(
        x, gate_w, gate_b, probs_out, idx_out, weight, eidx, rcnt, perm,
        te128, tr0128, trw128, te64, tr064, trw64, li);
    if (!all_mode) {
      prepack<<<dim3(32, 6, ENUM), 256, 0, stream>>>(
          wq, wk, wv, wo, w1, w2, Whi_p, Wlo_p, li, 0);
    }
    size_t plane = all_mode ? (size_t)li * PK_TOTAL : 0;
    ln_kernel<<<MTOT / 4, 256, 0, stream>>>(x, h_hi, h_lo, ln1_g, ln1_b, eidx, perm, li);
    gemm_mfma<0, 256, 256, 6, 128, MAXT128><<<dim3(6 * MAXT128), 256, 0, stream>>>(
        h_hi, h_lo, Whi_p, Wlo_p, plane + PK_WQ, (size_t)(ENUM * CH * CH),
        bq, bk, bv, q, k, v, nullptr,
        te128, tr0128, trw128, perm, li);
    attn_kernel<<<BNUM * ROWLEN, 256, 0, stream>>>(q, k, v, h_hi, h_lo);
    gemm_mfma<2, 256, 256, 2, 64, MAXT64><<<dim3(2 * MAXT64), 256, 0, stream>>>(
        h_hi, h_lo, Whi_p, Wlo_p, plane + PK_WO, 0,
        bo, nullptr, nullptr, nullptr, nullptr, nullptr,
        x, te64, tr064, trw64, perm, li);
    ln_kernel<<<MTOT / 4, 256, 0, stream>>>(x, h_hi, h_lo, ln2_g, ln2_b, eidx, perm, li);
    fused_mlp<<<dim3(MAXT64), 256, 0, stream>>>(
        h_hi, h_lo, Whi_p, Wlo_p, plane, b1, b2, out + (size_t)li * IMG,
        x, weight, te64, tr064, trw64, perm, li);
  }
}